// Round 2
// baseline (391.033 us; speedup 1.0000x reference)
//
#include <hip/hip_runtime.h>
#include <cstddef>
#include <cstdint>

// ---------------------------------------------------------------------------
// MultiHeadSelfAttention: x(4,2048,1024) fp32, W(3072,1024) fp32, Wo(1024,1024)
// Pipeline: cvt->bf16 | GEMM1 qkv | RoPE(Q,K) | transpose V | flash attn | GEMM2
// r12: attn occupancy fix. Was 512 blocks (paired q-tiles) = 2 blocks/CU =
// 20% occupancy with MfmaUtil 14 / VALU 30 (dependency-stall bound). Now one
// q-tile per block, grid (16,64)=1024 blocks = 4 blocks/CU (LDS 36KB x 4 =
// 144KB <= 160KB), long tiles dispatched first. s_setprio(1) around MFMA
// clusters (T5, +4-7% attn measured m191). GEMM kept at m97 structure.
// ---------------------------------------------------------------------------

typedef unsigned short u16;
typedef short bf16x8 __attribute__((ext_vector_type(8)));   // 8 bf16 = 4 VGPRs
typedef float f32x4 __attribute__((ext_vector_type(4)));

#define B_   4
#define L_   2048
#define H_   16
#define DH_  64
#define D_   1024
#define E3_  3072

__device__ __forceinline__ u16 f2bf(float f) {            // RNE f32 -> bf16
  unsigned int u = __float_as_uint(f);
  u += 0x7fffu + ((u >> 16) & 1u);
  return (u16)(u >> 16);
}
__device__ __forceinline__ float bf2f(u16 h) {
  return __uint_as_float(((unsigned int)h) << 16);
}
// round-half-up pack of two f32 -> bf16x2 (5 VALU ops)
__device__ __forceinline__ unsigned pk2(float a, float b) {
  return ((__float_as_uint(a) + 0x8000u) >> 16) |
         ((__float_as_uint(b) + 0x8000u) & 0xffff0000u);
}
__device__ __forceinline__ float fexp2(float x) {
#if __has_builtin(__builtin_amdgcn_exp2f)
  return __builtin_amdgcn_exp2f(x);
#else
  return exp2f(x);
#endif
}

// async global->LDS DMA, 16 bytes/lane. LDS dest = wave-uniform base + lane*16
__device__ __forceinline__ void gload_lds16(const void* g, void* l) {
  auto gp = reinterpret_cast<const uint32_t __attribute__((address_space(1)))*>(
      reinterpret_cast<uintptr_t>(g));
  auto lp = reinterpret_cast<uint32_t __attribute__((address_space(3)))*>(
      reinterpret_cast<uintptr_t>(l));
  __builtin_amdgcn_global_load_lds(gp, lp, 16, 0, 0);
}

// ---------------------------------------------------------------- cvt fp32->bf16
__global__ __launch_bounds__(256) void cvt_bf16(const float* __restrict__ in,
                                                u16* __restrict__ out, int n8) {
  int i = blockIdx.x * 256 + threadIdx.x;
  if (i >= n8) return;
  const float4* p = (const float4*)in;
  float4 a = p[2 * i], b = p[2 * i + 1];
  uint4 o;
  o.x = (unsigned)f2bf(a.x) | ((unsigned)f2bf(a.y) << 16);
  o.y = (unsigned)f2bf(a.z) | ((unsigned)f2bf(a.w) << 16);
  o.z = (unsigned)f2bf(b.x) | ((unsigned)f2bf(b.y) << 16);
  o.w = (unsigned)f2bf(b.z) | ((unsigned)f2bf(b.w) << 16);
  ((uint4*)out)[i] = o;
}

// ---------------------------------------------------------------- GEMM C = A * B^T
// 128x128 block tile, 4 waves (2x2 of 64x64), BK=32, m97 structure:
// global_load_lds width=16 into linear [128][32] u16 LDS (64 B rows).
template <bool OUT_BF16>
__global__ __launch_bounds__(256) void gemm_bt(const u16* __restrict__ A,
                                               const u16* __restrict__ Bm,
                                               void* __restrict__ C, int N, int K) {
  __shared__ __align__(16) u16 As[128 * 32];
  __shared__ __align__(16) u16 Bs[128 * 32];
  const int tid = threadIdx.x;
  const int lane = tid & 63, wave = tid >> 6;
  const int quad = lane >> 4, l15 = lane & 15;
  const int wm = (wave >> 1) << 6, wn = (wave & 1) << 6;
  const int m0 = blockIdx.y << 7, n0 = blockIdx.x << 7;

  f32x4 acc[4][4];
#pragma unroll
  for (int i = 0; i < 4; ++i)
#pragma unroll
    for (int j = 0; j < 4; ++j) acc[i][j] = {0.f, 0.f, 0.f, 0.f};

  const int sr = lane >> 2;           // row within 16-row DMA chunk
  const int sc = (lane & 3) * 8;      // u16 col chunk (16 B)

  for (int k0 = 0; k0 < K; k0 += 32) {
#pragma unroll
    for (int it = 0; it < 2; ++it) {
      const int chunk = wave * 2 + it;          // 0..7 (16 rows each)
      const int row = chunk * 16 + sr;
      gload_lds16(A + (size_t)(m0 + row) * K + k0 + sc, As + chunk * 512);
      gload_lds16(Bm + (size_t)(n0 + row) * K + k0 + sc, Bs + chunk * 512);
    }
    __syncthreads();                  // drains vmcnt(0): LDS tiles complete
    bf16x8 af[4], bfr[4];
#pragma unroll
    for (int i = 0; i < 4; ++i)
      af[i] = *(const bf16x8*)(As + (wm + i * 16 + l15) * 32 + quad * 8);
#pragma unroll
    for (int j = 0; j < 4; ++j)
      bfr[j] = *(const bf16x8*)(Bs + (wn + j * 16 + l15) * 32 + quad * 8);
#pragma unroll
    for (int i = 0; i < 4; ++i)
#pragma unroll
      for (int j = 0; j < 4; ++j)
        acc[i][j] = __builtin_amdgcn_mfma_f32_16x16x32_bf16(af[i], bfr[j],
                                                            acc[i][j], 0, 0, 0);
    __syncthreads();                  // readers done before next DMA overwrites
  }
#pragma unroll
  for (int i = 0; i < 4; ++i) {
    int row = m0 + wm + i * 16 + quad * 4;
#pragma unroll
    for (int j = 0; j < 4; ++j) {
      int col = n0 + wn + j * 16 + l15;
#pragma unroll
      for (int r = 0; r < 4; ++r) {
        if (OUT_BF16)
          ((u16*)C)[(size_t)(row + r) * N + col] = f2bf(acc[i][j][r]);
        else
          ((float*)C)[(size_t)(row + r) * N + col] = acc[i][j][r];
      }
    }
  }
}

// ---------------------------------------------------------------- RoPE on Q,K (in place, bf16)
__global__ __launch_bounds__(256) void rope_qk(u16* __restrict__ qkvb) {
  int i = blockIdx.x * 256 + threadIdx.x;   // 8,388,608 threads
  int d2 = i & 31;
  int h  = (i >> 5) & 15;
  int t  = (i >> 9) & 1;
  int bl = i >> 10;                          // b*L + l
  int l  = bl & (L_ - 1);
  size_t off = (size_t)bl * E3_ + t * D_ + h * DH_ + d2 * 2;
  float inv = exp2f((float)d2 * -0.5190512648261504f);
  float ang = (float)l * inv;
  float sn = __sinf(ang), cs = __cosf(ang);
  unsigned int v = *(const unsigned int*)(qkvb + off);
  float x1 = bf2f((u16)(v & 0xffffu)), x2 = bf2f((u16)(v >> 16));
  float o1 = x1 * cs - x2 * sn;
  float o2 = x2 * cs + x1 * sn;
  if (t == 0) { o1 *= 0.18033688011112042f; o2 *= 0.18033688011112042f; }
  *(unsigned int*)(qkvb + off) =
      (unsigned)f2bf(o1) | ((unsigned)f2bf(o2) << 16);
}

// ---------------------------------------------------------------- V transpose: (b,l,h,d)->(b,h,d,l)
__global__ __launch_bounds__(256) void transpose_v(const u16* __restrict__ qkvb,
                                                   u16* __restrict__ Vt) {
  __shared__ u16 tile[64 * 65];
  const int bh = blockIdx.x, b = bh >> 4, h = bh & 15;
  const int lbase = blockIdx.y << 6;
  const int tid = threadIdx.x;
#pragma unroll
  for (int i = 0; i < 16; ++i) {
    int flat = i * 256 + tid;
    int l = flat >> 6, d = flat & 63;
    tile[l * 65 + d] =
        qkvb[(size_t)(b * L_ + lbase + l) * E3_ + 2 * D_ + h * DH_ + d];
  }
  __syncthreads();
#pragma unroll
  for (int i = 0; i < 16; ++i) {
    int flat = i * 256 + tid;
    int d = flat >> 6, l = flat & 63;
    Vt[(size_t)(bh * DH_ + d) * L_ + lbase + l] = tile[l * 65 + d];
  }
}

// ---------------------------------------------------------------- flash attention (causal)
// grid (16 q-tiles, B*H), 4 waves; block x handles q-tile qt = 15-x (long
// tiles first). Wave owns 32 q-rows (2 m-tiles). Transposed MFMA dataflow:
// S^T=mfma(kf,qf), O^T=mfma(vf,pf), l^T=mfma(ones,pf).
__global__ __launch_bounds__(256) void attn(const u16* __restrict__ qkvb,
                                            const u16* __restrict__ Vt,
                                            u16* __restrict__ Ob) {
  __shared__ __align__(16) u16 Ks[64 * 72];        // [key][d]
  __shared__ __align__(16) u16 Vs[64 * 72];        // [d][key]
  __shared__ __align__(16) u16 Ps[4][32 * 72];     // per-wave P / O tile [q][.]
  const int bh = blockIdx.y, b = bh >> 4, h = bh & 15;
  const int tid = threadIdx.x;
  const int lane = tid & 63, wave = tid >> 6, quad = lane >> 4, l15 = lane & 15;
  const int r0 = tid >> 3, c0 = (tid & 7) * 8;     // staging: 32 rows x 8 chunks
  u16* pw = Ps[wave];

  bf16x8 ones;
#pragma unroll
  for (int i = 0; i < 8; ++i) ones[i] = (short)0x3F80;   // bf16 1.0

  const int qbase = (15 - blockIdx.x) << 7;        // long tile first

  // Q fragments: 2 m-tiles (layout [q=l15][k=quad*8+j])
  bf16x8 qf[2][2];
#pragma unroll
  for (int mt = 0; mt < 2; ++mt) {
    const u16* qp = qkvb +
        (size_t)(b * L_ + qbase + wave * 32 + mt * 16 + l15) * E3_ + h * DH_;
    qf[mt][0] = *(const bf16x8*)(qp + quad * 8);
    qf[mt][1] = *(const bf16x8*)(qp + 32 + quad * 8);
  }

  f32x4 acc[2][4], lacc[2];                // O^T tiles + l (col q=l15)
#pragma unroll
  for (int mt = 0; mt < 2; ++mt) {
    lacc[mt] = {0.f, 0.f, 0.f, 0.f};
#pragma unroll
    for (int j = 0; j < 4; ++j) acc[mt][j] = {0.f, 0.f, 0.f, 0.f};
  }

  // prefetch k-tile 0 into registers
  uint4 kreg[2], vreg[2];
#pragma unroll
  for (int it = 0; it < 2; ++it) {
    int row = r0 + it * 32;
    kreg[it] = *(const uint4*)(qkvb + (size_t)(b * L_ + row) * E3_ + D_ +
                               h * DH_ + c0);
    vreg[it] = *(const uint4*)(Vt + (size_t)(bh * DH_ + row) * L_ + c0);
  }

  const int kend = qbase + 128;
  for (int kb = 0; kb < kend; kb += 64) {
    __syncthreads();   // previous iteration's Ks/Vs readers done
#pragma unroll
    for (int it = 0; it < 2; ++it) {
      int row = r0 + it * 32;
      *(uint4*)(Ks + row * 72 + c0) = kreg[it];
      *(uint4*)(Vs + row * 72 + c0) = vreg[it];
    }
    __syncthreads();

    // prefetch next k-tile
    if (kb + 64 < kend) {
#pragma unroll
      for (int it = 0; it < 2; ++it) {
        int row = r0 + it * 32;
        kreg[it] = *(const uint4*)(qkvb +
                                   (size_t)(b * L_ + kb + 64 + row) * E3_ +
                                   D_ + h * DH_ + c0);
        vreg[it] = *(const uint4*)(Vt + (size_t)(bh * DH_ + row) * L_ +
                                   kb + 64 + c0);
      }
    }

    // S^T = mfma(kf, qf): lane holds col q=l15, rows key=t*16+quad*4+r
    f32x4 st[2][4];
#pragma unroll
    for (int mt = 0; mt < 2; ++mt)
#pragma unroll
      for (int t = 0; t < 4; ++t) st[mt][t] = {0.f, 0.f, 0.f, 0.f};
    __builtin_amdgcn_s_setprio(1);
#pragma unroll
    for (int ks = 0; ks < 2; ++ks) {
      bf16x8 kf[4];
#pragma unroll
      for (int t = 0; t < 4; ++t)
        kf[t] =
            *(const bf16x8*)(Ks + (t * 16 + l15) * 72 + ks * 32 + quad * 8);
#pragma unroll
      for (int mt = 0; mt < 2; ++mt)
#pragma unroll
        for (int t = 0; t < 4; ++t)
          st[mt][t] = __builtin_amdgcn_mfma_f32_16x16x32_bf16(
              kf[t], qf[mt][ks], st[mt][t], 0, 0, 0);
    }
    __builtin_amdgcn_s_setprio(0);

    // p = exp2(s) (masked -> 0), packed b64 store to P[q][key]
#pragma unroll
    for (int mt = 0; mt < 2; ++mt) {
      const int rb = qbase + wave * 32 + mt * 16;
      const int qg = rb + l15;                 // this lane's global q row
      const bool dg = (kb + 63 > rb);          // diagonal overlap
#pragma unroll
      for (int t = 0; t < 4; ++t) {
        const int kg0 = kb + t * 16 + quad * 4;
        float p0, p1, p2, p3;
        if (dg) {
          p0 = (kg0 + 0 > qg) ? 0.f : fexp2(st[mt][t][0]);
          p1 = (kg0 + 1 > qg) ? 0.f : fexp2(st[mt][t][1]);
          p2 = (kg0 + 2 > qg) ? 0.f : fexp2(st[mt][t][2]);
          p3 = (kg0 + 3 > qg) ? 0.f : fexp2(st[mt][t][3]);
        } else {
          p0 = fexp2(st[mt][t][0]);
          p1 = fexp2(st[mt][t][1]);
          p2 = fexp2(st[mt][t][2]);
          p3 = fexp2(st[mt][t][3]);
        }
        uint2 pkd = {pk2(p0, p1), pk2(p2, p3)};
        *(uint2*)(pw + (mt * 16 + l15) * 72 + t * 16 + quad * 4) = pkd;
      }
    }
    __threadfence_block();   // same-wave LDS write -> read ordering

    // O^T += mfma(vf, pf) ; l += mfma(ones, pf)
    __builtin_amdgcn_s_setprio(1);
#pragma unroll
    for (int ks = 0; ks < 2; ++ks) {
      bf16x8 vf[4];
#pragma unroll
      for (int j = 0; j < 4; ++j)
        vf[j] =
            *(const bf16x8*)(Vs + (j * 16 + l15) * 72 + ks * 32 + quad * 8);
#pragma unroll
      for (int mt = 0; mt < 2; ++mt) {
        bf16x8 pf =
            *(const bf16x8*)(pw + (mt * 16 + l15) * 72 + ks * 32 + quad * 8);
        lacc[mt] = __builtin_amdgcn_mfma_f32_16x16x32_bf16(ones, pf,
                                                           lacc[mt], 0, 0, 0);
#pragma unroll
        for (int j = 0; j < 4; ++j)
          acc[mt][j] = __builtin_amdgcn_mfma_f32_16x16x32_bf16(
              vf[j], pf, acc[mt][j], 0, 0, 0);
      }
    }
    __builtin_amdgcn_s_setprio(0);
  }

  // epilogue: O^T lane holds col q=l15, rows d=j*16+quad*4+r; lacc uniform
  // across regs -> one reciprocal per m-tile; packed b64 stores to [q][d].
#pragma unroll
  for (int mt = 0; mt < 2; ++mt) {
    const float rl = 1.0f / lacc[mt][0];
#pragma unroll
    for (int j = 0; j < 4; ++j) {
      uint2 od = {pk2(acc[mt][j][0] * rl, acc[mt][j][1] * rl),
                  pk2(acc[mt][j][2] * rl, acc[mt][j][3] * rl)};
      *(uint2*)(pw + (mt * 16 + l15) * 72 + j * 16 + quad * 4) = od;
    }
  }
  __syncthreads();   // all waves' O tiles staged
#pragma unroll
  for (int it = 0; it < 4; ++it) {
    int unit = it * 256 + tid;                 // 1024 units = 128 rows x 8
    int row = unit >> 3, ch = (unit & 7) * 8;
    *(uint4*)(Ob + (size_t)(b * L_ + qbase + row) * D_ + h * DH_ + ch) =
        *(const uint4*)(Ps[row >> 5] + (row & 31) * 72 + ch);
  }
}

// ---------------------------------------------------------------- launch
extern "C" void kernel_launch(void* const* d_in, const int* in_sizes, int n_in,
                              void* d_out, int out_size, void* d_ws, size_t ws_size,
                              hipStream_t stream) {
  const float* x  = (const float*)d_in[0];
  const float* W  = (const float*)d_in[1];
  const float* Wo = (const float*)d_in[2];
  float* out = (float*)d_out;

  char* ws = (char*)d_ws;
  u16* xb   = (u16*)(ws);                    // 16,777,216
  u16* Wb   = (u16*)(ws + 16777216);         //  6,291,456
  u16* Wob  = (u16*)(ws + 23068672);         //  2,097,152
  u16* qkvb = (u16*)(ws + 25165824);         // 50,331,648  (B,L,3,H,DH) bf16
  u16* Vt   = (u16*)(ws + 75497472);         // 16,777,216  (B,H,DH,L) bf16
  u16* Ob   = (u16*)(ws + 92274688);         // 16,777,216  (B,L,D) bf16

  cvt_bf16<<<4096, 256, 0, stream>>>(x, xb, 1048576);
  cvt_bf16<<<1536, 256, 0, stream>>>(W, Wb, 393216);
  cvt_bf16<<<512, 256, 0, stream>>>(Wo, Wob, 131072);

  gemm_bt<true><<<dim3(E3_ / 128, (B_ * L_) / 128), 256, 0, stream>>>(
      xb, Wb, qkvb, E3_, D_);

  rope_qk<<<32768, 256, 0, stream>>>(qkvb);
  transpose_v<<<dim3(B_ * H_, L_ / 64), 256, 0, stream>>>(qkvb, Vt);

  attn<<<dim3(16, B_ * H_), 256, 0, stream>>>(qkvb, Vt, Ob);

  gemm_bt<false><<<dim3(D_ / 128, (B_ * L_) / 128), 256, 0, stream>>>(
      Ob, Wob, out, D_, D_);
}

// Round 3
// 280.556 us; speedup vs baseline: 1.3938x; 1.3938x over previous
//
#include <hip/hip_runtime.h>
#include <cstddef>
#include <cstdint>

// ---------------------------------------------------------------------------
// MultiHeadSelfAttention: x(4,2048,1024) fp32, W(3072,1024) fp32, Wo(1024,1024)
// Pipeline: cvt->bf16 | GEMM1 qkv | RoPE(Q,K) | transpose V | flash attn | GEMM2
// r13: revert r12's imbalanced grid (load-imbalance tail: 64 long blocks on
// 256 CUs). Back to paired q-tiles (512 blocks, uniform 34 k-iters) but with
// 8 waves x 16 q-rows per block (512 threads) instead of 4 x 32: same total
// work & LDS (36KB), 2 blocks/CU -> 16 waves/CU = 4 waves/SIMD (was 2).
// Dependency stalls (MFMA->softmax->MFMA chain) now hidden by TLP.
// ---------------------------------------------------------------------------

typedef unsigned short u16;
typedef short bf16x8 __attribute__((ext_vector_type(8)));   // 8 bf16 = 4 VGPRs
typedef float f32x4 __attribute__((ext_vector_type(4)));

#define B_   4
#define L_   2048
#define H_   16
#define DH_  64
#define D_   1024
#define E3_  3072

__device__ __forceinline__ u16 f2bf(float f) {            // RNE f32 -> bf16
  unsigned int u = __float_as_uint(f);
  u += 0x7fffu + ((u >> 16) & 1u);
  return (u16)(u >> 16);
}
__device__ __forceinline__ float bf2f(u16 h) {
  return __uint_as_float(((unsigned int)h) << 16);
}
// round-half-up pack of two f32 -> bf16x2 (5 VALU ops)
__device__ __forceinline__ unsigned pk2(float a, float b) {
  return ((__float_as_uint(a) + 0x8000u) >> 16) |
         ((__float_as_uint(b) + 0x8000u) & 0xffff0000u);
}
__device__ __forceinline__ float fexp2(float x) {
#if __has_builtin(__builtin_amdgcn_exp2f)
  return __builtin_amdgcn_exp2f(x);
#else
  return exp2f(x);
#endif
}

// async global->LDS DMA, 16 bytes/lane. LDS dest = wave-uniform base + lane*16
__device__ __forceinline__ void gload_lds16(const void* g, void* l) {
  auto gp = reinterpret_cast<const uint32_t __attribute__((address_space(1)))*>(
      reinterpret_cast<uintptr_t>(g));
  auto lp = reinterpret_cast<uint32_t __attribute__((address_space(3)))*>(
      reinterpret_cast<uintptr_t>(l));
  __builtin_amdgcn_global_load_lds(gp, lp, 16, 0, 0);
}

// ---------------------------------------------------------------- cvt fp32->bf16
__global__ __launch_bounds__(256) void cvt_bf16(const float* __restrict__ in,
                                                u16* __restrict__ out, int n8) {
  int i = blockIdx.x * 256 + threadIdx.x;
  if (i >= n8) return;
  const float4* p = (const float4*)in;
  float4 a = p[2 * i], b = p[2 * i + 1];
  uint4 o;
  o.x = (unsigned)f2bf(a.x) | ((unsigned)f2bf(a.y) << 16);
  o.y = (unsigned)f2bf(a.z) | ((unsigned)f2bf(a.w) << 16);
  o.z = (unsigned)f2bf(b.x) | ((unsigned)f2bf(b.y) << 16);
  o.w = (unsigned)f2bf(b.z) | ((unsigned)f2bf(b.w) << 16);
  ((uint4*)out)[i] = o;
}

// ---------------------------------------------------------------- GEMM C = A * B^T
// 128x128 block tile, 4 waves (2x2 of 64x64), BK=32, m97 structure:
// global_load_lds width=16 into linear [128][32] u16 LDS (64 B rows).
template <bool OUT_BF16>
__global__ __launch_bounds__(256) void gemm_bt(const u16* __restrict__ A,
                                               const u16* __restrict__ Bm,
                                               void* __restrict__ C, int N, int K) {
  __shared__ __align__(16) u16 As[128 * 32];
  __shared__ __align__(16) u16 Bs[128 * 32];
  const int tid = threadIdx.x;
  const int lane = tid & 63, wave = tid >> 6;
  const int quad = lane >> 4, l15 = lane & 15;
  const int wm = (wave >> 1) << 6, wn = (wave & 1) << 6;
  const int m0 = blockIdx.y << 7, n0 = blockIdx.x << 7;

  f32x4 acc[4][4];
#pragma unroll
  for (int i = 0; i < 4; ++i)
#pragma unroll
    for (int j = 0; j < 4; ++j) acc[i][j] = {0.f, 0.f, 0.f, 0.f};

  const int sr = lane >> 2;           // row within 16-row DMA chunk
  const int sc = (lane & 3) * 8;      // u16 col chunk (16 B)

  for (int k0 = 0; k0 < K; k0 += 32) {
#pragma unroll
    for (int it = 0; it < 2; ++it) {
      const int chunk = wave * 2 + it;          // 0..7 (16 rows each)
      const int row = chunk * 16 + sr;
      gload_lds16(A + (size_t)(m0 + row) * K + k0 + sc, As + chunk * 512);
      gload_lds16(Bm + (size_t)(n0 + row) * K + k0 + sc, Bs + chunk * 512);
    }
    __syncthreads();                  // drains vmcnt(0): LDS tiles complete
    bf16x8 af[4], bfr[4];
#pragma unroll
    for (int i = 0; i < 4; ++i)
      af[i] = *(const bf16x8*)(As + (wm + i * 16 + l15) * 32 + quad * 8);
#pragma unroll
    for (int j = 0; j < 4; ++j)
      bfr[j] = *(const bf16x8*)(Bs + (wn + j * 16 + l15) * 32 + quad * 8);
#pragma unroll
    for (int i = 0; i < 4; ++i)
#pragma unroll
      for (int j = 0; j < 4; ++j)
        acc[i][j] = __builtin_amdgcn_mfma_f32_16x16x32_bf16(af[i], bfr[j],
                                                            acc[i][j], 0, 0, 0);
    __syncthreads();                  // readers done before next DMA overwrites
  }
#pragma unroll
  for (int i = 0; i < 4; ++i) {
    int row = m0 + wm + i * 16 + quad * 4;
#pragma unroll
    for (int j = 0; j < 4; ++j) {
      int col = n0 + wn + j * 16 + l15;
#pragma unroll
      for (int r = 0; r < 4; ++r) {
        if (OUT_BF16)
          ((u16*)C)[(size_t)(row + r) * N + col] = f2bf(acc[i][j][r]);
        else
          ((float*)C)[(size_t)(row + r) * N + col] = acc[i][j][r];
      }
    }
  }
}

// ---------------------------------------------------------------- RoPE on Q,K (in place, bf16)
__global__ __launch_bounds__(256) void rope_qk(u16* __restrict__ qkvb) {
  int i = blockIdx.x * 256 + threadIdx.x;   // 8,388,608 threads
  int d2 = i & 31;
  int h  = (i >> 5) & 15;
  int t  = (i >> 9) & 1;
  int bl = i >> 10;                          // b*L + l
  int l  = bl & (L_ - 1);
  size_t off = (size_t)bl * E3_ + t * D_ + h * DH_ + d2 * 2;
  float inv = exp2f((float)d2 * -0.5190512648261504f);
  float ang = (float)l * inv;
  float sn = __sinf(ang), cs = __cosf(ang);
  unsigned int v = *(const unsigned int*)(qkvb + off);
  float x1 = bf2f((u16)(v & 0xffffu)), x2 = bf2f((u16)(v >> 16));
  float o1 = x1 * cs - x2 * sn;
  float o2 = x2 * cs + x1 * sn;
  if (t == 0) { o1 *= 0.18033688011112042f; o2 *= 0.18033688011112042f; }
  *(unsigned int*)(qkvb + off) =
      (unsigned)f2bf(o1) | ((unsigned)f2bf(o2) << 16);
}

// ---------------------------------------------------------------- V transpose: (b,l,h,d)->(b,h,d,l)
__global__ __launch_bounds__(256) void transpose_v(const u16* __restrict__ qkvb,
                                                   u16* __restrict__ Vt) {
  __shared__ u16 tile[64 * 65];
  const int bh = blockIdx.x, b = bh >> 4, h = bh & 15;
  const int lbase = blockIdx.y << 6;
  const int tid = threadIdx.x;
#pragma unroll
  for (int i = 0; i < 16; ++i) {
    int flat = i * 256 + tid;
    int l = flat >> 6, d = flat & 63;
    tile[l * 65 + d] =
        qkvb[(size_t)(b * L_ + lbase + l) * E3_ + 2 * D_ + h * DH_ + d];
  }
  __syncthreads();
#pragma unroll
  for (int i = 0; i < 16; ++i) {
    int flat = i * 256 + tid;
    int d = flat >> 6, l = flat & 63;
    Vt[(size_t)(bh * DH_ + d) * L_ + lbase + l] = tile[l * 65 + d];
  }
}

// ---------------------------------------------------------------- flash attention (causal)
// grid (8 pairs, B*H), 8 waves x 512 threads; block (p,bh) runs 128-row
// q-tile 15-p then p (uniform 34 k-iters). Wave owns 16 q-rows (1 m-tile).
// Transposed MFMA dataflow: S^T=mfma(kf,qf), O^T=mfma(vf,pf), l=mfma(ones,pf).
__global__ __launch_bounds__(512) void attn(const u16* __restrict__ qkvb,
                                            const u16* __restrict__ Vt,
                                            u16* __restrict__ Ob) {
  __shared__ __align__(16) u16 Ks[64 * 72];        // [key][d]
  __shared__ __align__(16) u16 Vs[64 * 72];        // [d][key]
  __shared__ __align__(16) u16 Ps[8][16 * 72];     // per-wave P / O tile [q][.]
  const int bh = blockIdx.y, b = bh >> 4, h = bh & 15;
  const int pair = blockIdx.x;                     // 0..7
  const int tid = threadIdx.x;
  const int lane = tid & 63, wave = tid >> 6, quad = lane >> 4, l15 = lane & 15;
  const int r0 = tid >> 3, c0 = (tid & 7) * 8;     // staging: 64 rows x 8 chunks
  u16* pw = Ps[wave];

  bf16x8 ones;
#pragma unroll
  for (int i = 0; i < 8; ++i) ones[i] = (short)0x3F80;   // bf16 1.0

  for (int a = 0; a < 2; ++a) {
    const int qbase = (a ? pair : (15 - pair)) << 7;   // long tile first
    const int rb = qbase + wave * 16;                  // wave's q-row base
    const int qg = rb + l15;                           // this lane's q row

    // Q fragments (layout [q=l15][k=quad*8+j])
    bf16x8 qf[2];
    {
      const u16* qp = qkvb + (size_t)(b * L_ + qg) * E3_ + h * DH_;
      qf[0] = *(const bf16x8*)(qp + quad * 8);
      qf[1] = *(const bf16x8*)(qp + 32 + quad * 8);
    }

    f32x4 acc[4], lacc;                // O^T tile + l (col q=l15)
    lacc = {0.f, 0.f, 0.f, 0.f};
#pragma unroll
    for (int j = 0; j < 4; ++j) acc[j] = {0.f, 0.f, 0.f, 0.f};

    // prefetch k-tile 0 into registers (512 thr cover 64 rows x 128 B)
    uint4 kreg, vreg;
    kreg = *(const uint4*)(qkvb + (size_t)(b * L_ + r0) * E3_ + D_ +
                           h * DH_ + c0);
    vreg = *(const uint4*)(Vt + (size_t)(bh * DH_ + r0) * L_ + c0);

    const int kend = qbase + 128;
    for (int kb = 0; kb < kend; kb += 64) {
      __syncthreads();   // previous iteration's Ks/Vs readers done
      *(uint4*)(Ks + r0 * 72 + c0) = kreg;
      *(uint4*)(Vs + r0 * 72 + c0) = vreg;
      __syncthreads();

      // prefetch next k-tile
      if (kb + 64 < kend) {
        kreg = *(const uint4*)(qkvb + (size_t)(b * L_ + kb + 64 + r0) * E3_ +
                               D_ + h * DH_ + c0);
        vreg = *(const uint4*)(Vt + (size_t)(bh * DH_ + r0) * L_ + kb + 64 +
                               c0);
      }

      // S^T = mfma(kf, qf): lane holds col q=l15, rows key=t*16+quad*4+r
      f32x4 st[4];
#pragma unroll
      for (int t = 0; t < 4; ++t) st[t] = {0.f, 0.f, 0.f, 0.f};
      __builtin_amdgcn_s_setprio(1);
#pragma unroll
      for (int ks = 0; ks < 2; ++ks) {
        bf16x8 kf[4];
#pragma unroll
        for (int t = 0; t < 4; ++t)
          kf[t] =
              *(const bf16x8*)(Ks + (t * 16 + l15) * 72 + ks * 32 + quad * 8);
#pragma unroll
        for (int t = 0; t < 4; ++t)
          st[t] = __builtin_amdgcn_mfma_f32_16x16x32_bf16(kf[t], qf[ks],
                                                          st[t], 0, 0, 0);
      }
      __builtin_amdgcn_s_setprio(0);

      // p = exp2(s) (masked -> 0), packed b64 store to P[q][key]
      {
        const bool dg = (kb + 63 > rb);          // diagonal overlap
#pragma unroll
        for (int t = 0; t < 4; ++t) {
          const int kg0 = kb + t * 16 + quad * 4;
          float p0, p1, p2, p3;
          if (dg) {
            p0 = (kg0 + 0 > qg) ? 0.f : fexp2(st[t][0]);
            p1 = (kg0 + 1 > qg) ? 0.f : fexp2(st[t][1]);
            p2 = (kg0 + 2 > qg) ? 0.f : fexp2(st[t][2]);
            p3 = (kg0 + 3 > qg) ? 0.f : fexp2(st[t][3]);
          } else {
            p0 = fexp2(st[t][0]);
            p1 = fexp2(st[t][1]);
            p2 = fexp2(st[t][2]);
            p3 = fexp2(st[t][3]);
          }
          uint2 pkd = {pk2(p0, p1), pk2(p2, p3)};
          *(uint2*)(pw + l15 * 72 + t * 16 + quad * 4) = pkd;
        }
      }
      __threadfence_block();   // same-wave LDS write -> read ordering

      // O^T += mfma(vf, pf) ; l += mfma(ones, pf)
      __builtin_amdgcn_s_setprio(1);
#pragma unroll
      for (int ks = 0; ks < 2; ++ks) {
        bf16x8 vf[4];
#pragma unroll
        for (int j = 0; j < 4; ++j)
          vf[j] =
              *(const bf16x8*)(Vs + (j * 16 + l15) * 72 + ks * 32 + quad * 8);
        bf16x8 pf = *(const bf16x8*)(pw + l15 * 72 + ks * 32 + quad * 8);
        lacc = __builtin_amdgcn_mfma_f32_16x16x32_bf16(ones, pf, lacc,
                                                       0, 0, 0);
#pragma unroll
        for (int j = 0; j < 4; ++j)
          acc[j] = __builtin_amdgcn_mfma_f32_16x16x32_bf16(vf[j], pf,
                                                           acc[j], 0, 0, 0);
      }
      __builtin_amdgcn_s_setprio(0);
    }

    // epilogue: O^T lane holds col q=l15, rows d=j*16+quad*4+r; lacc uniform
    // across regs -> one reciprocal per wave; packed b64 stores to [q][d].
    {
      const float rl = 1.0f / lacc[0];
#pragma unroll
      for (int j = 0; j < 4; ++j) {
        uint2 od = {pk2(acc[j][0] * rl, acc[j][1] * rl),
                    pk2(acc[j][2] * rl, acc[j][3] * rl)};
        *(uint2*)(pw + l15 * 72 + j * 16 + quad * 4) = od;
      }
    }
    __syncthreads();   // all waves' O tiles staged
#pragma unroll
    for (int it = 0; it < 2; ++it) {
      int unit = it * 512 + tid;                 // 1024 units = 128 rows x 8
      int row = unit >> 3, ch = (unit & 7) * 8;
      *(uint4*)(Ob + (size_t)(b * L_ + qbase + row) * D_ + h * DH_ + ch) =
          *(const uint4*)(Ps[row >> 4] + (row & 15) * 72 + ch);
    }
    __syncthreads();   // store reads done before next tile overwrites Ps
  }
}

// ---------------------------------------------------------------- launch
extern "C" void kernel_launch(void* const* d_in, const int* in_sizes, int n_in,
                              void* d_out, int out_size, void* d_ws, size_t ws_size,
                              hipStream_t stream) {
  const float* x  = (const float*)d_in[0];
  const float* W  = (const float*)d_in[1];
  const float* Wo = (const float*)d_in[2];
  float* out = (float*)d_out;

  char* ws = (char*)d_ws;
  u16* xb   = (u16*)(ws);                    // 16,777,216
  u16* Wb   = (u16*)(ws + 16777216);         //  6,291,456
  u16* Wob  = (u16*)(ws + 23068672);         //  2,097,152
  u16* qkvb = (u16*)(ws + 25165824);         // 50,331,648  (B,L,3,H,DH) bf16
  u16* Vt   = (u16*)(ws + 75497472);         // 16,777,216  (B,H,DH,L) bf16
  u16* Ob   = (u16*)(ws + 92274688);         // 16,777,216  (B,L,D) bf16

  cvt_bf16<<<4096, 256, 0, stream>>>(x, xb, 1048576);
  cvt_bf16<<<1536, 256, 0, stream>>>(W, Wb, 393216);
  cvt_bf16<<<512, 256, 0, stream>>>(Wo, Wob, 131072);

  gemm_bt<true><<<dim3(E3_ / 128, (B_ * L_) / 128), 256, 0, stream>>>(
      xb, Wb, qkvb, E3_, D_);

  rope_qk<<<32768, 256, 0, stream>>>(qkvb);
  transpose_v<<<dim3(B_ * H_, L_ / 64), 256, 0, stream>>>(qkvb, Vt);

  attn<<<dim3(8, B_ * H_), 512, 0, stream>>>(qkvb, Vt, Ob);

  gemm_bt<false><<<dim3(D_ / 128, (B_ * L_) / 128), 256, 0, stream>>>(
      Ob, Wob, out, D_, D_);
}

// Round 4
// 277.702 us; speedup vs baseline: 1.4081x; 1.0103x over previous
//
#include <hip/hip_runtime.h>
#include <cstddef>
#include <cstdint>

// ---------------------------------------------------------------------------
// MultiHeadSelfAttention: x(4,2048,1024) fp32, W(3072,1024) fp32, Wo(1024,1024)
// Pipeline: cvt->bf16 | GEMM1 qkv | RoPE(Q,K) | transpose V | flash attn | GEMM2
// r14: attn K/V staging rework. Old staging wrote padded LDS via uint4 stores
// with an 8-way bank conflict (SQ_LDS_BANK_CONFLICT ~8.0M, constant across
// rounds). Now: unpadded [64][64] double-buffered K/V staged by
// global_load_lds width=16 (linear dest, conflict-free writes), XOR granule
// swizzle (src granule = (l&7)^(l>>3), read granule = G^(row&7)) keeps
// ds_read_b128 fragment loads 2-way (free). One barrier per k-iter (dbuf),
// DMA for tile t+1 issued at iter t start. threadfence -> lgkmcnt(0)+
// sched_barrier (doesn't drain the in-flight DMA). attn-only change.
// ---------------------------------------------------------------------------

typedef unsigned short u16;
typedef short bf16x8 __attribute__((ext_vector_type(8)));   // 8 bf16 = 4 VGPRs
typedef float f32x4 __attribute__((ext_vector_type(4)));

#define B_   4
#define L_   2048
#define H_   16
#define DH_  64
#define D_   1024
#define E3_  3072

__device__ __forceinline__ u16 f2bf(float f) {            // RNE f32 -> bf16
  unsigned int u = __float_as_uint(f);
  u += 0x7fffu + ((u >> 16) & 1u);
  return (u16)(u >> 16);
}
__device__ __forceinline__ float bf2f(u16 h) {
  return __uint_as_float(((unsigned int)h) << 16);
}
// round-half-up pack of two f32 -> bf16x2 (5 VALU ops)
__device__ __forceinline__ unsigned pk2(float a, float b) {
  return ((__float_as_uint(a) + 0x8000u) >> 16) |
         ((__float_as_uint(b) + 0x8000u) & 0xffff0000u);
}
__device__ __forceinline__ float fexp2(float x) {
#if __has_builtin(__builtin_amdgcn_exp2f)
  return __builtin_amdgcn_exp2f(x);
#else
  return exp2f(x);
#endif
}

// async global->LDS DMA, 16 bytes/lane. LDS dest = wave-uniform base + lane*16
__device__ __forceinline__ void gload_lds16(const void* g, void* l) {
  auto gp = reinterpret_cast<const uint32_t __attribute__((address_space(1)))*>(
      reinterpret_cast<uintptr_t>(g));
  auto lp = reinterpret_cast<uint32_t __attribute__((address_space(3)))*>(
      reinterpret_cast<uintptr_t>(l));
  __builtin_amdgcn_global_load_lds(gp, lp, 16, 0, 0);
}

// ---------------------------------------------------------------- cvt fp32->bf16
__global__ __launch_bounds__(256) void cvt_bf16(const float* __restrict__ in,
                                                u16* __restrict__ out, int n8) {
  int i = blockIdx.x * 256 + threadIdx.x;
  if (i >= n8) return;
  const float4* p = (const float4*)in;
  float4 a = p[2 * i], b = p[2 * i + 1];
  uint4 o;
  o.x = (unsigned)f2bf(a.x) | ((unsigned)f2bf(a.y) << 16);
  o.y = (unsigned)f2bf(a.z) | ((unsigned)f2bf(a.w) << 16);
  o.z = (unsigned)f2bf(b.x) | ((unsigned)f2bf(b.y) << 16);
  o.w = (unsigned)f2bf(b.z) | ((unsigned)f2bf(b.w) << 16);
  ((uint4*)out)[i] = o;
}

// ---------------------------------------------------------------- GEMM C = A * B^T
// 128x128 block tile, 4 waves (2x2 of 64x64), BK=32, m97 structure:
// global_load_lds width=16 into linear [128][32] u16 LDS (64 B rows).
template <bool OUT_BF16>
__global__ __launch_bounds__(256) void gemm_bt(const u16* __restrict__ A,
                                               const u16* __restrict__ Bm,
                                               void* __restrict__ C, int N, int K) {
  __shared__ __align__(16) u16 As[128 * 32];
  __shared__ __align__(16) u16 Bs[128 * 32];
  const int tid = threadIdx.x;
  const int lane = tid & 63, wave = tid >> 6;
  const int quad = lane >> 4, l15 = lane & 15;
  const int wm = (wave >> 1) << 6, wn = (wave & 1) << 6;
  const int m0 = blockIdx.y << 7, n0 = blockIdx.x << 7;

  f32x4 acc[4][4];
#pragma unroll
  for (int i = 0; i < 4; ++i)
#pragma unroll
    for (int j = 0; j < 4; ++j) acc[i][j] = {0.f, 0.f, 0.f, 0.f};

  const int sr = lane >> 2;           // row within 16-row DMA chunk
  const int sc = (lane & 3) * 8;      // u16 col chunk (16 B)

  for (int k0 = 0; k0 < K; k0 += 32) {
#pragma unroll
    for (int it = 0; it < 2; ++it) {
      const int chunk = wave * 2 + it;          // 0..7 (16 rows each)
      const int row = chunk * 16 + sr;
      gload_lds16(A + (size_t)(m0 + row) * K + k0 + sc, As + chunk * 512);
      gload_lds16(Bm + (size_t)(n0 + row) * K + k0 + sc, Bs + chunk * 512);
    }
    __syncthreads();                  // drains vmcnt(0): LDS tiles complete
    bf16x8 af[4], bfr[4];
#pragma unroll
    for (int i = 0; i < 4; ++i)
      af[i] = *(const bf16x8*)(As + (wm + i * 16 + l15) * 32 + quad * 8);
#pragma unroll
    for (int j = 0; j < 4; ++j)
      bfr[j] = *(const bf16x8*)(Bs + (wn + j * 16 + l15) * 32 + quad * 8);
#pragma unroll
    for (int i = 0; i < 4; ++i)
#pragma unroll
      for (int j = 0; j < 4; ++j)
        acc[i][j] = __builtin_amdgcn_mfma_f32_16x16x32_bf16(af[i], bfr[j],
                                                            acc[i][j], 0, 0, 0);
    __syncthreads();                  // readers done before next DMA overwrites
  }
#pragma unroll
  for (int i = 0; i < 4; ++i) {
    int row = m0 + wm + i * 16 + quad * 4;
#pragma unroll
    for (int j = 0; j < 4; ++j) {
      int col = n0 + wn + j * 16 + l15;
#pragma unroll
      for (int r = 0; r < 4; ++r) {
        if (OUT_BF16)
          ((u16*)C)[(size_t)(row + r) * N + col] = f2bf(acc[i][j][r]);
        else
          ((float*)C)[(size_t)(row + r) * N + col] = acc[i][j][r];
      }
    }
  }
}

// ---------------------------------------------------------------- RoPE on Q,K (in place, bf16)
__global__ __launch_bounds__(256) void rope_qk(u16* __restrict__ qkvb) {
  int i = blockIdx.x * 256 + threadIdx.x;   // 8,388,608 threads
  int d2 = i & 31;
  int h  = (i >> 5) & 15;
  int t  = (i >> 9) & 1;
  int bl = i >> 10;                          // b*L + l
  int l  = bl & (L_ - 1);
  size_t off = (size_t)bl * E3_ + t * D_ + h * DH_ + d2 * 2;
  float inv = exp2f((float)d2 * -0.5190512648261504f);
  float ang = (float)l * inv;
  float sn = __sinf(ang), cs = __cosf(ang);
  unsigned int v = *(const unsigned int*)(qkvb + off);
  float x1 = bf2f((u16)(v & 0xffffu)), x2 = bf2f((u16)(v >> 16));
  float o1 = x1 * cs - x2 * sn;
  float o2 = x2 * cs + x1 * sn;
  if (t == 0) { o1 *= 0.18033688011112042f; o2 *= 0.18033688011112042f; }
  *(unsigned int*)(qkvb + off) =
      (unsigned)f2bf(o1) | ((unsigned)f2bf(o2) << 16);
}

// ---------------------------------------------------------------- V transpose: (b,l,h,d)->(b,h,d,l)
__global__ __launch_bounds__(256) void transpose_v(const u16* __restrict__ qkvb,
                                                   u16* __restrict__ Vt) {
  __shared__ u16 tile[64 * 65];
  const int bh = blockIdx.x, b = bh >> 4, h = bh & 15;
  const int lbase = blockIdx.y << 6;
  const int tid = threadIdx.x;
#pragma unroll
  for (int i = 0; i < 16; ++i) {
    int flat = i * 256 + tid;
    int l = flat >> 6, d = flat & 63;
    tile[l * 65 + d] =
        qkvb[(size_t)(b * L_ + lbase + l) * E3_ + 2 * D_ + h * DH_ + d];
  }
  __syncthreads();
#pragma unroll
  for (int i = 0; i < 16; ++i) {
    int flat = i * 256 + tid;
    int d = flat >> 6, l = flat & 63;
    Vt[(size_t)(bh * DH_ + d) * L_ + lbase + l] = tile[l * 65 + d];
  }
}

// ---------------------------------------------------------------- flash attention (causal)
// grid (8 pairs, B*H), 8 waves x 512 threads; block (p,bh) runs 128-row
// q-tile 15-p then p (uniform 34 k-iters). Wave owns 16 q-rows (1 m-tile).
// Transposed MFMA dataflow: S^T=mfma(kf,qf), O^T=mfma(vf,pf), l=mfma(ones,pf).
// K/V: unpadded [64][64] dbuf LDS, staged via global_load_lds (wave w stages
// rows w*8..w*8+7; lane l -> row w*8+(l>>3), 16B granule l&7, source granule
// pre-swizzled (l&7)^(l>>3)). Reads use granule G^(row&7). One barrier/iter.
__global__ __launch_bounds__(512) void attn(const u16* __restrict__ qkvb,
                                            const u16* __restrict__ Vt,
                                            u16* __restrict__ Ob) {
  __shared__ __align__(16) u16 Ks[2][64 * 64];     // [dbuf][key][d], XOR-swz
  __shared__ __align__(16) u16 Vs[2][64 * 64];     // [dbuf][d][key], XOR-swz
  __shared__ __align__(16) u16 Ps[8][16 * 72];     // per-wave P / O tile [q][.]
  const int bh = blockIdx.y, b = bh >> 4, h = bh & 15;
  const int pair = blockIdx.x;                     // 0..7
  const int tid = threadIdx.x;
  const int lane = tid & 63, wave = tid >> 6, quad = lane >> 4, l15 = lane & 15;
  u16* pw = Ps[wave];

  // DMA staging: wave w covers rows w*8..w*8+7 of the 64-row tile.
  const int srow = wave * 8 + (lane >> 3);          // row this lane sources
  const int sgran = (lane & 7) ^ (lane >> 3);       // pre-swizzled 16B granule
  const u16* ksrc0 =
      qkvb + (size_t)(b * L_ + srow) * E3_ + D_ + h * DH_ + sgran * 8;
  const u16* vsrc0 = Vt + (size_t)(bh * DH_ + srow) * L_ + sgran * 8;
  const int ldst = wave * 512;                      // per-wave uniform LDS dest

  bf16x8 ones;
#pragma unroll
  for (int i = 0; i < 8; ++i) ones[i] = (short)0x3F80;   // bf16 1.0

  for (int a = 0; a < 2; ++a) {
    const int qbase = (a ? pair : (15 - pair)) << 7;   // long tile first
    const int rb = qbase + wave * 16;                  // wave's q-row base
    const int qg = rb + l15;                           // this lane's q row

    // Q fragments (layout [q=l15][k=quad*8+j])
    bf16x8 qf[2];
    {
      const u16* qp = qkvb + (size_t)(b * L_ + qg) * E3_ + h * DH_;
      qf[0] = *(const bf16x8*)(qp + quad * 8);
      qf[1] = *(const bf16x8*)(qp + 32 + quad * 8);
    }

    f32x4 acc[4], lacc;                // O^T tile + l (col q=l15)
    lacc = {0.f, 0.f, 0.f, 0.f};
#pragma unroll
    for (int j = 0; j < 4; ++j) acc[j] = {0.f, 0.f, 0.f, 0.f};

    // prologue: DMA k-tile 0 into buf 0
    gload_lds16(ksrc0, Ks[0] + ldst);
    gload_lds16(vsrc0, Vs[0] + ldst);
    __syncthreads();                   // drain DMA (vmcnt 0) + rendezvous

    const int kend = qbase + 128;
    int cur = 0;
    for (int kb = 0; kb < kend; kb += 64, cur ^= 1) {
      // issue DMA for next tile into the idle buffer (free since the barrier
      // at the end of iter kb-64 separated its last readers)
      if (kb + 64 < kend) {
        gload_lds16(ksrc0 + (size_t)(kb + 64) * E3_, Ks[cur ^ 1] + ldst);
        gload_lds16(vsrc0 + (kb + 64), Vs[cur ^ 1] + ldst);
      }
      const u16* kcur = Ks[cur];
      const u16* vcur = Vs[cur];

      // S^T = mfma(kf, qf): lane holds col q=l15, rows key=t*16+quad*4+r
      f32x4 st[4];
#pragma unroll
      for (int t = 0; t < 4; ++t) st[t] = {0.f, 0.f, 0.f, 0.f};
      __builtin_amdgcn_s_setprio(1);
#pragma unroll
      for (int ks = 0; ks < 2; ++ks) {
        bf16x8 kf[4];
#pragma unroll
        for (int t = 0; t < 4; ++t)
          kf[t] = *(const bf16x8*)(kcur + (t * 16 + l15) * 64 +
                                   (((ks * 4 + quad) ^ (l15 & 7)) * 8));
#pragma unroll
        for (int t = 0; t < 4; ++t)
          st[t] = __builtin_amdgcn_mfma_f32_16x16x32_bf16(kf[t], qf[ks],
                                                          st[t], 0, 0, 0);
      }
      __builtin_amdgcn_s_setprio(0);

      // p = exp2(s) (masked -> 0), packed b64 store to P[q][key]
      {
        const bool dg = (kb + 63 > rb);          // diagonal overlap
#pragma unroll
        for (int t = 0; t < 4; ++t) {
          const int kg0 = kb + t * 16 + quad * 4;
          float p0, p1, p2, p3;
          if (dg) {
            p0 = (kg0 + 0 > qg) ? 0.f : fexp2(st[t][0]);
            p1 = (kg0 + 1 > qg) ? 0.f : fexp2(st[t][1]);
            p2 = (kg0 + 2 > qg) ? 0.f : fexp2(st[t][2]);
            p3 = (kg0 + 3 > qg) ? 0.f : fexp2(st[t][3]);
          } else {
            p0 = fexp2(st[t][0]);
            p1 = fexp2(st[t][1]);
            p2 = fexp2(st[t][2]);
            p3 = fexp2(st[t][3]);
          }
          uint2 pkd = {pk2(p0, p1), pk2(p2, p3)};
          *(uint2*)(pw + l15 * 72 + t * 16 + quad * 4) = pkd;
        }
      }
      // same-wave LDS write -> read ordering without draining the DMA (vmcnt)
      asm volatile("s_waitcnt lgkmcnt(0)" ::: "memory");
      __builtin_amdgcn_sched_barrier(0);

      // O^T += mfma(vf, pf) ; l += mfma(ones, pf)
      __builtin_amdgcn_s_setprio(1);
#pragma unroll
      for (int ks = 0; ks < 2; ++ks) {
        bf16x8 vf[4];
#pragma unroll
        for (int j = 0; j < 4; ++j)
          vf[j] = *(const bf16x8*)(vcur + (j * 16 + l15) * 64 +
                                   (((ks * 4 + quad) ^ (l15 & 7)) * 8));
        bf16x8 pf = *(const bf16x8*)(pw + l15 * 72 + ks * 32 + quad * 8);
        lacc = __builtin_amdgcn_mfma_f32_16x16x32_bf16(ones, pf, lacc,
                                                       0, 0, 0);
#pragma unroll
        for (int j = 0; j < 4; ++j)
          acc[j] = __builtin_amdgcn_mfma_f32_16x16x32_bf16(vf[j], pf,
                                                           acc[j], 0, 0, 0);
      }
      __builtin_amdgcn_s_setprio(0);

      __syncthreads();   // buf[cur] readers done; buf[cur^1] DMA complete
    }

    // epilogue: O^T lane holds col q=l15, rows d=j*16+quad*4+r; lacc uniform
    // across regs -> one reciprocal per wave; packed b64 stores to [q][d].
    {
      const float rl = 1.0f / lacc[0];
#pragma unroll
      for (int j = 0; j < 4; ++j) {
        uint2 od = {pk2(acc[j][0] * rl, acc[j][1] * rl),
                    pk2(acc[j][2] * rl, acc[j][3] * rl)};
        *(uint2*)(pw + l15 * 72 + j * 16 + quad * 4) = od;
      }
    }
    __syncthreads();   // all waves' O tiles staged
#pragma unroll
    for (int it = 0; it < 2; ++it) {
      int unit = it * 512 + tid;                 // 1024 units = 128 rows x 8
      int row = unit >> 3, ch = (unit & 7) * 8;
      *(uint4*)(Ob + (size_t)(b * L_ + qbase + row) * D_ + h * DH_ + ch) =
          *(const uint4*)(Ps[row >> 4] + (row & 15) * 72 + ch);
    }
    __syncthreads();   // store reads done before next tile overwrites Ps
  }
}

// ---------------------------------------------------------------- launch
extern "C" void kernel_launch(void* const* d_in, const int* in_sizes, int n_in,
                              void* d_out, int out_size, void* d_ws, size_t ws_size,
                              hipStream_t stream) {
  const float* x  = (const float*)d_in[0];
  const float* W  = (const float*)d_in[1];
  const float* Wo = (const float*)d_in[2];
  float* out = (float*)d_out;

  char* ws = (char*)d_ws;
  u16* xb   = (u16*)(ws);                    // 16,777,216
  u16* Wb   = (u16*)(ws + 16777216);         //  6,291,456
  u16* Wob  = (u16*)(ws + 23068672);         //  2,097,152
  u16* qkvb = (u16*)(ws + 25165824);         // 50,331,648  (B,L,3,H,DH) bf16
  u16* Vt   = (u16*)(ws + 75497472);         // 16,777,216  (B,H,DH,L) bf16
  u16* Ob   = (u16*)(ws + 92274688);         // 16,777,216  (B,L,D) bf16

  cvt_bf16<<<4096, 256, 0, stream>>>(x, xb, 1048576);
  cvt_bf16<<<1536, 256, 0, stream>>>(W, Wb, 393216);
  cvt_bf16<<<512, 256, 0, stream>>>(Wo, Wob, 131072);

  gemm_bt<true><<<dim3(E3_ / 128, (B_ * L_) / 128), 256, 0, stream>>>(
      xb, Wb, qkvb, E3_, D_);

  rope_qk<<<32768, 256, 0, stream>>>(qkvb);
  transpose_v<<<dim3(B_ * H_, L_ / 64), 256, 0, stream>>>(qkvb, Vt);

  attn<<<dim3(8, B_ * H_), 512, 0, stream>>>(qkvb, Vt, Ob);

  gemm_bt<false><<<dim3(D_ / 128, (B_ * L_) / 128), 256, 0, stream>>>(
      Ob, Wob, out, D_, D_);
}